// Round 1
// baseline (461.196 us; speedup 1.0000x reference)
//
#include <hip/hip_runtime.h>
#include <stdint.h>
#include <stddef.h>

// Problem dims (fixed)
#define TT 2048
#define NH 16
#define HD 64
#define CM 1024            // d_model
#define MROWS 8192         // B*T

typedef float f32x4  __attribute__((ext_vector_type(4)));
typedef short bf16x8 __attribute__((ext_vector_type(8)));

static __device__ __forceinline__ unsigned short f32_to_bf16(float f) {
    union { float f; unsigned u; } c; c.f = f;
    unsigned u = c.u;
    u += 0x7FFFu + ((u >> 16) & 1u);   // RNE
    return (unsigned short)(u >> 16);
}

// ---------------------------------------------------------------- casts
__global__ __launch_bounds__(256) void cast_f32_bf16(
    const float* __restrict__ in, unsigned short* __restrict__ out, int n4) {
    int i = blockIdx.x * blockDim.x + threadIdx.x;
    if (i >= n4) return;
    float4 v = ((const float4*)in)[i];
    ushort4 o;
    o.x = f32_to_bf16(v.x); o.y = f32_to_bf16(v.y);
    o.z = f32_to_bf16(v.z); o.w = f32_to_bf16(v.w);
    ((ushort4*)out)[i] = o;
}

// ---------------------------------------------------------------- GEMM core
// C[128x128] = A[128xK] * B^T where B stored [N][K] (both bf16, K-contiguous).
// 4 waves in 2x2; each wave does a 64x64 tile as 4x4 MFMA 16x16x32 tiles.
#define LDT 40   // padded LDS row stride (32 + 8 bf16) -> 16B-aligned chunks

__device__ __forceinline__ void gemm_core_128x128(
    const unsigned short* __restrict__ A,
    const unsigned short* __restrict__ Bm,
    int K, int m0, int n0,
    unsigned short* ldsA, unsigned short* ldsB,
    f32x4 acc[4][4])
{
    const int tid  = threadIdx.x;
    const int lane = tid & 63;
    const int w    = tid >> 6;
    const int wm   = (w >> 1) * 64;
    const int wn   = (w & 1) * 64;
    const int l15  = lane & 15;
    const int quad = lane >> 4;

    for (int k0 = 0; k0 < K; k0 += 32) {
        // stage 128x32 A-tile and B-tile (8 KB each), 16B per thread x2
        #pragma unroll
        for (int i = 0; i < 2; ++i) {
            int ch  = tid + i * 256;     // 512 chunks of 8 bf16
            int row = ch >> 2;
            int cc  = ch & 3;
            uint4 va = *(const uint4*)(A + (size_t)(m0 + row) * K + k0 + cc * 8);
            *(uint4*)(ldsA + row * LDT + cc * 8) = va;
            uint4 vb = *(const uint4*)(Bm + (size_t)(n0 + row) * K + k0 + cc * 8);
            *(uint4*)(ldsB + row * LDT + cc * 8) = vb;
        }
        __syncthreads();

        bf16x8 af[4], bfr[4];
        #pragma unroll
        for (int mi = 0; mi < 4; ++mi)
            af[mi] = *(const bf16x8*)(ldsA + (wm + mi * 16 + l15) * LDT + quad * 8);
        #pragma unroll
        for (int ni = 0; ni < 4; ++ni)
            bfr[ni] = *(const bf16x8*)(ldsB + (wn + ni * 16 + l15) * LDT + quad * 8);

        #pragma unroll
        for (int mi = 0; mi < 4; ++mi)
            #pragma unroll
            for (int ni = 0; ni < 4; ++ni)
                acc[mi][ni] = __builtin_amdgcn_mfma_f32_16x16x32_bf16(
                    af[mi], bfr[ni], acc[mi][ni], 0, 0, 0);
        __syncthreads();
    }
}

// ---------------------------------------------------------------- QKV GEMM
// X[8192,1024]*W^T -> [8192,3072]; scatter into Q[B,H,T,64] (x0.125),
// K[B,H,T,64], V^T[B,H,64,T], all bf16.
__global__ __launch_bounds__(256) void gemm_qkv(
    const unsigned short* __restrict__ X,
    const unsigned short* __restrict__ W,
    const float* __restrict__ bias,
    unsigned short* __restrict__ Qb,
    unsigned short* __restrict__ Kb,
    unsigned short* __restrict__ Vt)
{
    __shared__ unsigned short ldsA[128 * LDT];
    __shared__ unsigned short ldsB[128 * LDT];
    const int m0 = blockIdx.y * 128;
    const int n0 = blockIdx.x * 128;

    f32x4 acc[4][4];
    f32x4 z = {0.f, 0.f, 0.f, 0.f};
    #pragma unroll
    for (int mi = 0; mi < 4; ++mi)
        #pragma unroll
        for (int ni = 0; ni < 4; ++ni) acc[mi][ni] = z;

    gemm_core_128x128(X, W, CM, m0, n0, ldsA, ldsB, acc);

    const int tid  = threadIdx.x;
    const int lane = tid & 63;
    const int w    = tid >> 6;
    const int wm   = (w >> 1) * 64;
    const int wn   = (w & 1) * 64;
    const int l15  = lane & 15;
    const int quad = lane >> 4;
    const int region = n0 >> 10;   // 0=Q 1=K 2=V (128 | 1024)

    #pragma unroll
    for (int ni = 0; ni < 4; ++ni) {
        const int o   = n0 + wn + ni * 16 + l15;       // 0..3071
        const float bv = bias[o];
        const int oin = o & 1023;
        const int h = oin >> 6, d = oin & 63;
        #pragma unroll
        for (int mi = 0; mi < 4; ++mi) {
            #pragma unroll
            for (int r = 0; r < 4; ++r) {
                const int gm = m0 + wm + mi * 16 + quad * 4 + r;
                const int b  = gm >> 11, t = gm & 2047;
                const float val = acc[mi][ni][r] + bv;
                const int bh = (b << 4) + h;
                if (region == 0)
                    Qb[(((size_t)bh * TT + t) << 6) + d] = f32_to_bf16(val * 0.125f);
                else if (region == 1)
                    Kb[(((size_t)bh * TT + t) << 6) + d] = f32_to_bf16(val);
                else
                    Vt[(((size_t)bh << 6) + d) * TT + t] = f32_to_bf16(val);
            }
        }
    }
}

// ---------------------------------------------------------------- attention
// One block = 64 Q rows of one (b,h); 4 waves x 16 rows. Flash/online softmax
// over K-tiles of 64. P goes C-layout -> LDS -> A-layout (m120 pattern).
__global__ __launch_bounds__(256) void attn_kernel(
    const unsigned short* __restrict__ Qb,
    const unsigned short* __restrict__ Kb,
    const unsigned short* __restrict__ Vt,
    unsigned short* __restrict__ CTX)
{
    __shared__ unsigned short Kl[64 * 72];
    __shared__ unsigned short Vl[64 * 72];
    __shared__ unsigned short Pl[4 * 16 * 72];

    const int qt = blockIdx.x, h = blockIdx.y, b = blockIdx.z;
    const int q0 = qt * 64;
    const int tid  = threadIdx.x;
    const int lane = tid & 63;
    const int w    = tid >> 6;
    const int l15  = lane & 15;
    const int quad = lane >> 4;
    const int bh   = b * NH + h;

    // Q fragments for this wave's 16 rows (A-layout: m=l15, k=quad*8+j)
    const unsigned short* qrow = Qb + ((size_t)(bh * TT + q0 + w * 16 + l15)) * HD;
    const bf16x8 qf0 = *(const bf16x8*)(qrow + quad * 8);
    const bf16x8 qf1 = *(const bf16x8*)(qrow + 32 + quad * 8);

    f32x4 o_acc[4];
    f32x4 z = {0.f, 0.f, 0.f, 0.f};
    #pragma unroll
    for (int di = 0; di < 4; ++di) o_acc[di] = z;
    float mrow[4] = {-1e30f, -1e30f, -1e30f, -1e30f};
    float lrow[4] = {0.f, 0.f, 0.f, 0.f};
    const int q_r0 = q0 + w * 16 + quad * 4;

    for (int kt = 0; kt <= qt; ++kt) {
        const int kb = kt * 64;
        #pragma unroll
        for (int i = 0; i < 2; ++i) {
            int ch = tid + i * 256;       // 512 chunks: 64 rows x 8
            int row = ch >> 3, cc = ch & 7;
            *(uint4*)(Kl + row * 72 + cc * 8) =
                *(const uint4*)(Kb + ((size_t)(bh * TT + kb + row)) * HD + cc * 8);
            *(uint4*)(Vl + row * 72 + cc * 8) =
                *(const uint4*)(Vt + ((size_t)(bh * HD + row)) * TT + kb + cc * 8);
        }
        __syncthreads();

        // S = Q K^T (scale pre-folded into Q)
        f32x4 s[4];
        #pragma unroll
        for (int ni = 0; ni < 4; ++ni) {
            f32x4 a = z;
            bf16x8 kf0 = *(const bf16x8*)(Kl + (ni * 16 + l15) * 72 + quad * 8);
            bf16x8 kf1 = *(const bf16x8*)(Kl + (ni * 16 + l15) * 72 + 32 + quad * 8);
            a = __builtin_amdgcn_mfma_f32_16x16x32_bf16(qf0, kf0, a, 0, 0, 0);
            a = __builtin_amdgcn_mfma_f32_16x16x32_bf16(qf1, kf1, a, 0, 0, 0);
            s[ni] = a;
        }

        // causal mask + online softmax (rows owned: q_r0+r; cols kb+ni*16+l15)
        #pragma unroll
        for (int r = 0; r < 4; ++r) {
            const int qa = q_r0 + r;
            float vmax = -1e30f;
            #pragma unroll
            for (int ni = 0; ni < 4; ++ni) {
                const int col = kb + ni * 16 + l15;
                float sv = s[ni][r];
                sv = (col > qa) ? -1e30f : sv;
                s[ni][r] = sv;
                vmax = fmaxf(vmax, sv);
            }
            vmax = fmaxf(vmax, __shfl_xor(vmax, 1));
            vmax = fmaxf(vmax, __shfl_xor(vmax, 2));
            vmax = fmaxf(vmax, __shfl_xor(vmax, 4));
            vmax = fmaxf(vmax, __shfl_xor(vmax, 8));
            const float mnew  = fmaxf(mrow[r], vmax);
            const float alpha = __expf(mrow[r] - mnew);
            mrow[r] = mnew;
            float rsum = 0.f;
            #pragma unroll
            for (int ni = 0; ni < 4; ++ni) {
                const float p = __expf(s[ni][r] - mnew);
                s[ni][r] = p;
                rsum += p;
            }
            rsum += __shfl_xor(rsum, 1);
            rsum += __shfl_xor(rsum, 2);
            rsum += __shfl_xor(rsum, 4);
            rsum += __shfl_xor(rsum, 8);
            lrow[r] = lrow[r] * alpha + rsum;
            #pragma unroll
            for (int di = 0; di < 4; ++di) o_acc[di][r] *= alpha;
        }

        // P: C-layout regs -> per-wave LDS (bf16); same-wave RAW, no barrier
        unsigned short* pw = Pl + w * (16 * 72);
        #pragma unroll
        for (int ni = 0; ni < 4; ++ni)
            #pragma unroll
            for (int r = 0; r < 4; ++r)
                pw[(quad * 4 + r) * 72 + ni * 16 + l15] = f32_to_bf16(s[ni][r]);

        // O += P V  (A = P from LDS, B = V^T tile, k-contiguous)
        #pragma unroll
        for (int c = 0; c < 2; ++c) {
            bf16x8 pf = *(const bf16x8*)(pw + l15 * 72 + c * 32 + quad * 8);
            #pragma unroll
            for (int di = 0; di < 4; ++di) {
                bf16x8 vf = *(const bf16x8*)(Vl + (di * 16 + l15) * 72 + c * 32 + quad * 8);
                o_acc[di] = __builtin_amdgcn_mfma_f32_16x16x32_bf16(pf, vf, o_acc[di], 0, 0, 0);
            }
        }
        __syncthreads();   // protect Kl/Vl before next stage
    }

    // epilogue: ctx[b,t, h*64+d] = O/l (bf16)
    #pragma unroll
    for (int di = 0; di < 4; ++di) {
        const int col = h * HD + di * 16 + l15;
        #pragma unroll
        for (int r = 0; r < 4; ++r) {
            const int t = q0 + w * 16 + quad * 4 + r;
            const float inv = 1.0f / lrow[r];
            CTX[((size_t)(b * TT + t)) * CM + col] = f32_to_bf16(o_acc[di][r] * inv);
        }
    }
}

// ---------------------------------------------------------------- out proj
__global__ __launch_bounds__(256) void gemm_out(
    const unsigned short* __restrict__ CTX,
    const unsigned short* __restrict__ W,
    const float* __restrict__ bias,
    float* __restrict__ out)
{
    __shared__ unsigned short ldsA[128 * LDT];
    __shared__ unsigned short ldsB[128 * LDT];
    const int m0 = blockIdx.y * 128;
    const int n0 = blockIdx.x * 128;

    f32x4 acc[4][4];
    f32x4 z = {0.f, 0.f, 0.f, 0.f};
    #pragma unroll
    for (int mi = 0; mi < 4; ++mi)
        #pragma unroll
        for (int ni = 0; ni < 4; ++ni) acc[mi][ni] = z;

    gemm_core_128x128(CTX, W, CM, m0, n0, ldsA, ldsB, acc);

    const int tid  = threadIdx.x;
    const int lane = tid & 63;
    const int w    = tid >> 6;
    const int wm   = (w >> 1) * 64;
    const int wn   = (w & 1) * 64;
    const int l15  = lane & 15;
    const int quad = lane >> 4;

    #pragma unroll
    for (int ni = 0; ni < 4; ++ni) {
        const int o = n0 + wn + ni * 16 + l15;
        const float bv = bias[o];
        #pragma unroll
        for (int mi = 0; mi < 4; ++mi) {
            #pragma unroll
            for (int r = 0; r < 4; ++r) {
                const int gm = m0 + wm + mi * 16 + quad * 4 + r;
                out[(size_t)gm * CM + o] = acc[mi][ni][r] + bv;
            }
        }
    }
}

// ---------------------------------------------------------------- launch
extern "C" void kernel_launch(void* const* d_in, const int* in_sizes, int n_in,
                              void* d_out, int out_size, void* d_ws, size_t ws_size,
                              hipStream_t stream) {
    const float* x     = (const float*)d_in[0];
    const float* qkv_w = (const float*)d_in[1];
    const float* qkv_b = (const float*)d_in[2];
    const float* out_w = (const float*)d_in[3];
    const float* out_b = (const float*)d_in[4];
    float* out = (float*)d_out;

    char* ws = (char*)d_ws;
    unsigned short* X16 = (unsigned short*)(ws + 0);         // 16 MB
    unsigned short* W1  = (unsigned short*)(ws + 16777216);  // 6 MB
    unsigned short* W2  = (unsigned short*)(ws + 23068672);  // 2 MB
    unsigned short* Qb  = (unsigned short*)(ws + 25165824);  // 16 MB
    unsigned short* Kb  = (unsigned short*)(ws + 41943040);  // 16 MB
    unsigned short* Vt  = (unsigned short*)(ws + 58720256);  // 16 MB
    unsigned short* CTX = (unsigned short*)(ws + 75497472);  // 16 MB  (total ~92 MB)

    cast_f32_bf16<<<8192, 256, 0, stream>>>(x,     X16, 8388608 / 4);
    cast_f32_bf16<<<3072, 256, 0, stream>>>(qkv_w, W1,  3145728 / 4);
    cast_f32_bf16<<<1024, 256, 0, stream>>>(out_w, W2,  1048576 / 4);

    gemm_qkv<<<dim3(24, 64), 256, 0, stream>>>(X16, W1, qkv_b, Qb, Kb, Vt);
    attn_kernel<<<dim3(TT / 64, NH, 4), 256, 0, stream>>>(Qb, Kb, Vt, CTX);
    gemm_out<<<dim3(8, 64), 256, 0, stream>>>(CTX, W2, out_b, out);
}

// Round 2
// 375.180 us; speedup vs baseline: 1.2293x; 1.2293x over previous
//
#include <hip/hip_runtime.h>
#include <stdint.h>
#include <stddef.h>

// Problem dims (fixed)
#define TT 2048
#define NH 16
#define HD 64
#define CM 1024            // d_model
#define QSCALE 0.1803368801f   // 0.125 * log2(e): softmax done in exp2 domain

typedef float f32x4  __attribute__((ext_vector_type(4)));
typedef short bf16x8 __attribute__((ext_vector_type(8)));

static __device__ __forceinline__ unsigned short f32_to_bf16(float f) {
    union { float f; unsigned u; } c; c.f = f;
    unsigned u = c.u;
    u += 0x7FFFu + ((u >> 16) & 1u);   // RNE
    return (unsigned short)(u >> 16);
}

// async global->LDS, 16B per lane. LDS dest = wave-uniform base + lane*16.
static __device__ __forceinline__ void glds16(const unsigned short* g, unsigned short* l) {
    __builtin_amdgcn_global_load_lds(
        (const __attribute__((address_space(1))) unsigned int*)g,
        (__attribute__((address_space(3))) unsigned int*)l,
        16, 0, 0);
}

// ---------------------------------------------------------------- casts
__global__ __launch_bounds__(256) void cast_f32_bf16(
    const float* __restrict__ in, unsigned short* __restrict__ out, int n4) {
    int i = blockIdx.x * blockDim.x + threadIdx.x;
    if (i >= n4) return;
    float4 v = ((const float4*)in)[i];
    ushort4 o;
    o.x = f32_to_bf16(v.x); o.y = f32_to_bf16(v.y);
    o.z = f32_to_bf16(v.z); o.w = f32_to_bf16(v.w);
    ((ushort4*)out)[i] = o;
}

// ---------------------------------------------------------------- GEMM core
// C[128x128] = A[128xK] * B^T, B stored [N][K] (bf16, K-contiguous).
// 4 waves 2x2, each wave 64x64 via 4x4 MFMA 16x16x32 tiles.
// LDS tiles UNPADDED [128][32] (required by global_load_lds lane-contiguity).
__device__ __forceinline__ void gemm_core_128x128(
    const unsigned short* __restrict__ A,
    const unsigned short* __restrict__ Bm,
    int K, int m0, int n0,
    unsigned short* ldsA, unsigned short* ldsB,
    f32x4 acc[4][4])
{
    const int tid  = threadIdx.x;
    const int lane = tid & 63;
    const int wm   = ((tid >> 6) >> 1) * 64;
    const int wn   = ((tid >> 6) & 1) * 64;
    const int l15  = lane & 15;
    const int quad = lane >> 4;

    // chunk c (16B = 8 bf16): row = c>>2, col8 = c&3; lds offset = c*8 shorts
    const int c1 = tid, c2 = tid + 256;
    const unsigned short* gA1 = A  + (size_t)(m0 + (c1 >> 2)) * K + (c1 & 3) * 8;
    const unsigned short* gA2 = A  + (size_t)(m0 + (c2 >> 2)) * K + (c2 & 3) * 8;
    const unsigned short* gB1 = Bm + (size_t)(n0 + (c1 >> 2)) * K + (c1 & 3) * 8;
    const unsigned short* gB2 = Bm + (size_t)(n0 + (c2 >> 2)) * K + (c2 & 3) * 8;
    unsigned short* dA1 = ldsA + (c1 & ~63) * 8;   // wave-uniform base
    unsigned short* dA2 = ldsA + (c2 & ~63) * 8;
    unsigned short* dB1 = ldsB + (c1 & ~63) * 8;
    unsigned short* dB2 = ldsB + (c2 & ~63) * 8;

    for (int k0 = 0; k0 < K; k0 += 32) {
        glds16(gA1 + k0, dA1);
        glds16(gA2 + k0, dA2);
        glds16(gB1 + k0, dB1);
        glds16(gB2 + k0, dB2);
        __syncthreads();                     // drains vmcnt -> LDS valid

        bf16x8 af[4], bfr[4];
        #pragma unroll
        for (int mi = 0; mi < 4; ++mi)
            af[mi] = *(const bf16x8*)(ldsA + (wm + mi * 16 + l15) * 32 + quad * 8);
        #pragma unroll
        for (int ni = 0; ni < 4; ++ni)
            bfr[ni] = *(const bf16x8*)(ldsB + (wn + ni * 16 + l15) * 32 + quad * 8);

        #pragma unroll
        for (int mi = 0; mi < 4; ++mi)
            #pragma unroll
            for (int ni = 0; ni < 4; ++ni)
                acc[mi][ni] = __builtin_amdgcn_mfma_f32_16x16x32_bf16(
                    af[mi], bfr[ni], acc[mi][ni], 0, 0, 0);
        __syncthreads();
    }
}

// ---------------------------------------------------------------- QKV GEMM
__global__ __launch_bounds__(256) void gemm_qkv(
    const unsigned short* __restrict__ X,
    const unsigned short* __restrict__ W,
    const float* __restrict__ bias,
    unsigned short* __restrict__ Qb,
    unsigned short* __restrict__ Kb,
    unsigned short* __restrict__ Vt)
{
    __shared__ __align__(16) unsigned short ldsA[128 * 32];
    __shared__ __align__(16) unsigned short ldsB[128 * 32];
    const int m0 = blockIdx.y * 128;
    const int n0 = blockIdx.x * 128;

    f32x4 acc[4][4];
    f32x4 z = {0.f, 0.f, 0.f, 0.f};
    #pragma unroll
    for (int mi = 0; mi < 4; ++mi)
        #pragma unroll
        for (int ni = 0; ni < 4; ++ni) acc[mi][ni] = z;

    gemm_core_128x128(X, W, CM, m0, n0, ldsA, ldsB, acc);

    const int tid  = threadIdx.x;
    const int lane = tid & 63;
    const int w    = tid >> 6;
    const int wm   = (w >> 1) * 64;
    const int wn   = (w & 1) * 64;
    const int l15  = lane & 15;
    const int quad = lane >> 4;
    const int region = n0 >> 10;   // 0=Q 1=K 2=V

    #pragma unroll
    for (int ni = 0; ni < 4; ++ni) {
        const int o   = n0 + wn + ni * 16 + l15;       // 0..3071
        const float bv = bias[o];
        const int oin = o & 1023;
        const int h = oin >> 6, d = oin & 63;
        #pragma unroll
        for (int mi = 0; mi < 4; ++mi) {
            #pragma unroll
            for (int r = 0; r < 4; ++r) {
                const int gm = m0 + wm + mi * 16 + quad * 4 + r;
                const int b  = gm >> 11, t = gm & 2047;
                const float val = acc[mi][ni][r] + bv;
                const int bh = (b << 4) + h;
                if (region == 0)
                    Qb[(((size_t)bh * TT + t) << 6) + d] = f32_to_bf16(val * QSCALE);
                else if (region == 1)
                    Kb[(((size_t)bh * TT + t) << 6) + d] = f32_to_bf16(val);
                else
                    Vt[(((size_t)bh << 6) + d) * TT + t] = f32_to_bf16(val);
            }
        }
    }
}

// ---------------------------------------------------------------- attention
// Block = 64 q-rows of one (b,h); 4 waves x 16 q. S computed TRANSPOSED:
// mfma(K_frag, Q_frag) -> D[t][q], col q = l15, so each lane owns ONE query
// row: softmax = in-lane reduce + 2 shfls; m/l/alpha are per-lane scalars.
// PV as O^T = mfma(V^T_frag, P_frag). Q pre-scaled by 0.125*log2e -> exp2.
__global__ __launch_bounds__(256) void attn_kernel(
    const unsigned short* __restrict__ Qb,
    const unsigned short* __restrict__ Kb,
    const unsigned short* __restrict__ Vt,
    unsigned short* __restrict__ CTX)
{
    __shared__ __align__(16) unsigned short Kl[64 * 72];
    __shared__ __align__(16) unsigned short Vl[64 * 72];
    __shared__ __align__(16) unsigned short Pl[4 * 16 * 72];

    const int qt = (int)gridDim.x - 1 - (int)blockIdx.x;  // heavy blocks first
    const int h = blockIdx.y, b = blockIdx.z;
    const int q0 = qt * 64;
    const int tid  = threadIdx.x;
    const int lane = tid & 63;
    const int w    = tid >> 6;
    const int l15  = lane & 15;
    const int quad = lane >> 4;
    const int bh   = b * NH + h;
    const int qloc = w * 16 + l15;          // this lane's query (local)

    // Q fragment: lane l15 = query row, k (=d) contiguous
    const unsigned short* qrow = Qb + (size_t)(bh * TT + q0 + qloc) * HD;
    const bf16x8 qf0 = *(const bf16x8*)(qrow + quad * 8);
    const bf16x8 qf1 = *(const bf16x8*)(qrow + 32 + quad * 8);

    f32x4 o_acc[4];
    f32x4 z = {0.f, 0.f, 0.f, 0.f};
    #pragma unroll
    for (int di = 0; di < 4; ++di) o_acc[di] = z;
    float mrun = -1e30f, lrun = 0.f;

    for (int kt = 0; kt <= qt; ++kt) {
        const int kb = kt * 64;
        #pragma unroll
        for (int i = 0; i < 2; ++i) {
            int ch = tid + i * 256;          // 512 chunks: 64 rows x 8
            int row = ch >> 3, cc = ch & 7;
            *(uint4*)(Kl + row * 72 + cc * 8) =
                *(const uint4*)(Kb + (size_t)(bh * TT + kb + row) * HD + cc * 8);
            *(uint4*)(Vl + row * 72 + cc * 8) =
                *(const uint4*)(Vt + (size_t)(bh * HD + row) * TT + kb + cc * 8);
        }
        __syncthreads();

        // S^T[t][q]: rows t = ni*16 + quad*4 + r, col q = l15
        f32x4 s[4];
        #pragma unroll
        for (int ni = 0; ni < 4; ++ni) {
            f32x4 a = z;
            const unsigned short* kr = Kl + (ni * 16 + l15) * 72;
            bf16x8 kf0 = *(const bf16x8*)(kr + quad * 8);
            bf16x8 kf1 = *(const bf16x8*)(kr + 32 + quad * 8);
            a = __builtin_amdgcn_mfma_f32_16x16x32_bf16(kf0, qf0, a, 0, 0, 0);
            a = __builtin_amdgcn_mfma_f32_16x16x32_bf16(kf1, qf1, a, 0, 0, 0);
            s[ni] = a;
        }

        // causal mask: only the diagonal tile needs it
        if (kt == qt) {
            #pragma unroll
            for (int ni = 0; ni < 4; ++ni)
                #pragma unroll
                for (int r = 0; r < 4; ++r)
                    if (ni * 16 + quad * 4 + r > qloc) s[ni][r] = -1e30f;
        }

        // online softmax, one query per lane
        float vmax = -1e30f;
        #pragma unroll
        for (int ni = 0; ni < 4; ++ni)
            #pragma unroll
            for (int r = 0; r < 4; ++r) vmax = fmaxf(vmax, s[ni][r]);
        vmax = fmaxf(vmax, __shfl_xor(vmax, 16));
        vmax = fmaxf(vmax, __shfl_xor(vmax, 32));
        const float mnew  = fmaxf(mrun, vmax);
        const float alpha = __builtin_amdgcn_exp2f(mrun - mnew);
        mrun = mnew;
        float psum = 0.f;
        #pragma unroll
        for (int ni = 0; ni < 4; ++ni)
            #pragma unroll
            for (int r = 0; r < 4; ++r) {
                float p = __builtin_amdgcn_exp2f(s[ni][r] - mnew);
                s[ni][r] = p;
                psum += p;
            }
        psum += __shfl_xor(psum, 16);
        psum += __shfl_xor(psum, 32);
        lrun = lrun * alpha + psum;
        #pragma unroll
        for (int di = 0; di < 4; ++di) o_acc[di] *= alpha;

        // P^T -> LDS as [q_local16][t 0..63], 4 contiguous t per write (b64)
        unsigned short* pw = Pl + w * (16 * 72);
        #pragma unroll
        for (int ni = 0; ni < 4; ++ni) {
            uint2 pk;
            pk.x = (unsigned)f32_to_bf16(s[ni][0]) | ((unsigned)f32_to_bf16(s[ni][1]) << 16);
            pk.y = (unsigned)f32_to_bf16(s[ni][2]) | ((unsigned)f32_to_bf16(s[ni][3]) << 16);
            *(uint2*)(pw + l15 * 72 + ni * 16 + quad * 4) = pk;
        }
        asm volatile("s_waitcnt lgkmcnt(0)" ::: "memory");  // same-wave LDS RAW

        // O^T[d][q] += V^T[d][t] * P[q][t]
        #pragma unroll
        for (int c = 0; c < 2; ++c) {
            bf16x8 pf = *(const bf16x8*)(pw + l15 * 72 + c * 32 + quad * 8);
            #pragma unroll
            for (int di = 0; di < 4; ++di) {
                bf16x8 vf = *(const bf16x8*)(Vl + (di * 16 + l15) * 72 + c * 32 + quad * 8);
                o_acc[di] = __builtin_amdgcn_mfma_f32_16x16x32_bf16(vf, pf, o_acc[di], 0, 0, 0);
            }
        }
        __syncthreads();   // protect Kl/Vl before next stage
    }

    // epilogue: one query row per lane; 4 contiguous d per 8B store
    const float inv = 1.0f / lrun;
    unsigned short* crow = CTX + (size_t)(b * TT + q0 + qloc) * CM + h * HD;
    #pragma unroll
    for (int di = 0; di < 4; ++di) {
        uint2 pk;
        pk.x = (unsigned)f32_to_bf16(o_acc[di][0] * inv) |
               ((unsigned)f32_to_bf16(o_acc[di][1] * inv) << 16);
        pk.y = (unsigned)f32_to_bf16(o_acc[di][2] * inv) |
               ((unsigned)f32_to_bf16(o_acc[di][3] * inv) << 16);
        *(uint2*)(crow + di * 16 + quad * 4) = pk;
    }
}

// ---------------------------------------------------------------- out proj
__global__ __launch_bounds__(256) void gemm_out(
    const unsigned short* __restrict__ CTX,
    const unsigned short* __restrict__ W,
    const float* __restrict__ bias,
    float* __restrict__ out)
{
    __shared__ __align__(16) unsigned short ldsA[128 * 32];
    __shared__ __align__(16) unsigned short ldsB[128 * 32];
    const int m0 = blockIdx.y * 128;
    const int n0 = blockIdx.x * 128;

    f32x4 acc[4][4];
    f32x4 z = {0.f, 0.f, 0.f, 0.f};
    #pragma unroll
    for (int mi = 0; mi < 4; ++mi)
        #pragma unroll
        for (int ni = 0; ni < 4; ++ni) acc[mi][ni] = z;

    gemm_core_128x128(CTX, W, CM, m0, n0, ldsA, ldsB, acc);

    const int tid  = threadIdx.x;
    const int lane = tid & 63;
    const int w    = tid >> 6;
    const int wm   = (w >> 1) * 64;
    const int wn   = (w & 1) * 64;
    const int l15  = lane & 15;
    const int quad = lane >> 4;

    #pragma unroll
    for (int ni = 0; ni < 4; ++ni) {
        const int o = n0 + wn + ni * 16 + l15;
        const float bv = bias[o];
        #pragma unroll
        for (int mi = 0; mi < 4; ++mi) {
            #pragma unroll
            for (int r = 0; r < 4; ++r) {
                const int gm = m0 + wm + mi * 16 + quad * 4 + r;
                out[(size_t)gm * CM + o] = acc[mi][ni][r] + bv;
            }
        }
    }
}

// ---------------------------------------------------------------- launch
extern "C" void kernel_launch(void* const* d_in, const int* in_sizes, int n_in,
                              void* d_out, int out_size, void* d_ws, size_t ws_size,
                              hipStream_t stream) {
    const float* x     = (const float*)d_in[0];
    const float* qkv_w = (const float*)d_in[1];
    const float* qkv_b = (const float*)d_in[2];
    const float* out_w = (const float*)d_in[3];
    const float* out_b = (const float*)d_in[4];
    float* out = (float*)d_out;

    char* ws = (char*)d_ws;
    unsigned short* X16 = (unsigned short*)(ws + 0);         // 16 MB
    unsigned short* W1  = (unsigned short*)(ws + 16777216);  // 6 MB
    unsigned short* W2  = (unsigned short*)(ws + 23068672);  // 2 MB
    unsigned short* Qb  = (unsigned short*)(ws + 25165824);  // 16 MB
    unsigned short* Kb  = (unsigned short*)(ws + 41943040);  // 16 MB
    unsigned short* Vt  = (unsigned short*)(ws + 58720256);  // 16 MB
    unsigned short* CTX = (unsigned short*)(ws + 75497472);  // 16 MB  (~92 MB)

    cast_f32_bf16<<<8192, 256, 0, stream>>>(x,     X16, 8388608 / 4);
    cast_f32_bf16<<<3072, 256, 0, stream>>>(qkv_w, W1,  3145728 / 4);
    cast_f32_bf16<<<1024, 256, 0, stream>>>(out_w, W2,  1048576 / 4);

    gemm_qkv<<<dim3(24, 64), 256, 0, stream>>>(X16, W1, qkv_b, Qb, Kb, Vt);
    attn_kernel<<<dim3(TT / 64, NH, 4), 256, 0, stream>>>(Qb, Kb, Vt, CTX);
    gemm_out<<<dim3(8, 64), 256, 0, stream>>>(CTX, W2, out_b, out);
}